// Round 1
// baseline (237.621 us; speedup 1.0000x reference)
//
#include <hip/hip_runtime.h>
#include <math.h>

#define NTHREADS 256               // 4 fully-independent waves per block
#define WPB      4                 // rows (waves) per block; NO barriers anywhere
#define NELEM    4096              // H*W
#define EPL      64                // keys per lane -> whole row in one wave
#define NREP1    4                 // pass-1 replicas per wave (lane & 3)
#define HSTRIDE  260               // words; %4==0 (uint4-aligned), %32==4 (replica bank spread)
#define WAVE_LDS (NREP1 * HSTRIDE) // 1040 words per wave; tails reuse replica 0/1 space
#define LDSW     (WPB * WAVE_LDS)  // 4160 words = 16.6 KB/block

typedef float v4f __attribute__((ext_vector_type(4)));

// order-preserving float->uint map (ascending), branchless 3-op forms
__device__ __forceinline__ unsigned f2ord(float f) {
    unsigned u = __float_as_uint(f);
    return u ^ ((unsigned)((int)u >> 31) | 0x80000000u);
}
__device__ __forceinline__ float ord2f(unsigned k) {
    return __uint_as_float(k ^ (~(unsigned)((int)k >> 31) | 0x80000000u));
}

// Canonical GCN wave64 inclusive add-scan in the VALU pipe via DPP.
__device__ __forceinline__ unsigned iscan_dpp(unsigned v) {
    v += (unsigned)__builtin_amdgcn_update_dpp(0, (int)v, 0x111, 0xF, 0xF, false);
    v += (unsigned)__builtin_amdgcn_update_dpp(0, (int)v, 0x112, 0xF, 0xF, false);
    v += (unsigned)__builtin_amdgcn_update_dpp(0, (int)v, 0x114, 0xF, 0xF, false);
    v += (unsigned)__builtin_amdgcn_update_dpp(0, (int)v, 0x118, 0xF, 0xF, false);
    v += (unsigned)__builtin_amdgcn_update_dpp(0, (int)v, 0x142, 0xA, 0xF, false);
    v += (unsigned)__builtin_amdgcn_update_dpp(0, (int)v, 0x143, 0xC, 0xF, false);
    return v;
}

struct Pick2 { unsigned a, b; };

// Reduce NR replicas of 256 bins (4 bins/lane), DPP-scan, locate ranks rA,rB.
// Wave-uniform packed result (bucket<<12)|newrank via ballot + v_readlane.
template <int NR>
__device__ __forceinline__ Pick2 wave_pick2(const unsigned* region, int lane,
                                            unsigned rA, unsigned rB) {
    unsigned s0 = 0, s1 = 0, s2 = 0, s3 = 0;
    #pragma unroll
    for (int rep = 0; rep < NR; ++rep) {
        uint4 h = ((const uint4*)(region + rep * HSTRIDE))[lane];
        s0 += h.x; s1 += h.y; s2 += h.z; s3 += h.w;
    }
    unsigned tot = s0 + s1 + s2 + s3;
    unsigned inc = iscan_dpp(tot);
    unsigned ex  = inc - tot;          // exclusive base of this lane's 4 bins
    unsigned base[4] = {ex, ex + s0, ex + s0 + s1, ex + s0 + s1 + s2};
    unsigned cnt[4]  = {s0, s1, s2, s3};
    unsigned resA = 0, resB = 0;
    bool fA = false, fB = false;
    #pragma unroll
    for (int j = 0; j < 4; ++j) {
        if (rA >= base[j] && rA < base[j] + cnt[j]) {
            resA = ((unsigned)(4 * lane + j) << 12) | (rA - base[j]); fA = true;
        }
        if (rB >= base[j] && rB < base[j] + cnt[j]) {
            resB = ((unsigned)(4 * lane + j) << 12) | (rB - base[j]); fB = true;
        }
    }
    unsigned long long mA = __ballot(fA);
    unsigned long long mB = __ballot(fB);
    Pick2 r;
    r.a = (unsigned)__builtin_amdgcn_readlane((int)resA, (int)(__ffsll((long long)mA) - 1));
    r.b = (unsigned)__builtin_amdgcn_readlane((int)resB, (int)(__ffsll((long long)mB) - 1));
    return r;
}

__global__ void __launch_bounds__(NTHREADS, 4)
xsrelu_kernel(const float* __restrict__ x, const float* __restrict__ plogit,
              float* __restrict__ out, int C, int nrows) {
    __shared__ __align__(16) unsigned hist[LDSW];   // wave-private regions, no sharing

    const int tid  = threadIdx.x;
    const int wid  = tid >> 6;         // 0..3 -> independent row per wave
    const int lane = tid & 63;
    const int row  = blockIdx.x * WPB + wid;
    if (row >= nrows) return;          // wave-uniform; no barriers exist to violate

    unsigned* wbase = hist + wid * WAVE_LDS;

    // Load row (coalesced float4, 1 KB per instruction); 64 keys/lane in VGPRs.
    const float4* xr = (const float4*)(x + (size_t)row * NELEM);
    unsigned k[EPL];
    #pragma unroll
    for (int j = 0; j < EPL / 4; ++j) {
        float4 v = xr[j * 64 + lane];
        k[4 * j + 0] = f2ord(v.x);
        k[4 * j + 1] = f2ord(v.y);
        k[4 * j + 2] = f2ord(v.z);
        k[4 * j + 3] = f2ord(v.w);
    }

    // p0 -> scalar rank indices; pc -> interpolation weight. (row-uniform -> SGPRs)
    float p0 = 1.0f / (1.0f + expf(-plogit[0]));
    float pc = 1.0f / (1.0f + expf(-plogit[row % C]));
    int kLow  = min(max((int)((float)NELEM * (p0 - 0.02f)), 0), NELEM - 1);
    int kHigh = min(max((int)((float)NELEM * (p0 + 0.02f)), 0), NELEM - 1);

    // ---- Pass 1 (bits 31..24), NREP1 replicas, all wave-private.
    // Same-wave DS ops execute in order: zero -> atomics -> pick reads need no barrier.
    unsigned* my1 = wbase + (lane & (NREP1 - 1)) * HSTRIDE;
    const uint4 z4 = make_uint4(0u, 0u, 0u, 0u);
    #pragma unroll
    for (int r = 0; r < NREP1; ++r)
        ((uint4*)(wbase + r * HSTRIDE))[lane] = z4;   // bins 0..255 of each replica
    #pragma unroll
    for (int j = 0; j < EPL; ++j)
        atomicAdd(&my1[k[j] >> 24], 1u);
    Pick2 p1 = wave_pick2<NREP1>(wbase, lane, (unsigned)kLow, (unsigned)kHigh);
    unsigned bA = p1.a >> 12, bB = p1.b >> 12;
    unsigned prefA = bA << 24, rA = p1.a & 0xFFFu;
    unsigned prefB = bB << 24, rB = p1.b & 0xFFFu;
    unsigned known = 0xFF000000u;
    bool diverged = (bA != bB);        // wave-uniform (from readlane)

    // ---- Passes 2..4: tail histograms reuse replica 0 (A) / replica 1 (B) space.
    unsigned* myT = wbase;
    unsigned* myB = wbase + HSTRIDE;
    #pragma unroll 1
    for (int shift = 16; shift >= 0; shift -= 8) {
        if (!diverged) {               // row-uniform branch
            ((uint4*)myT)[lane] = z4;
            #pragma unroll
            for (int j = 0; j < EPL; ++j) {
                unsigned kk = k[j];
                if ((kk & known) == prefA)
                    atomicAdd(&myT[(kk >> shift) & 0xFFu], 1u);
            }
            Pick2 p = wave_pick2<1>(myT, lane, rA, rB);
            unsigned cA = p.a >> 12, cB = p.b >> 12;
            prefA |= cA << shift;  rA = p.a & 0xFFFu;
            prefB |= cB << shift;  rB = p.b & 0xFFFu;
            diverged = (cA != cB);
        } else {
            ((uint4*)myT)[lane] = z4;
            ((uint4*)myB)[lane] = z4;
            // single scan, cndmask-selected destination region (A xor B match)
            #pragma unroll
            for (int j = 0; j < EPL; ++j) {
                unsigned kk = k[j];
                unsigned km = kk & known;
                bool isB = (km == prefB);
                if ((km == prefA) | isB)
                    atomicAdd((isB ? myB : myT) + ((kk >> shift) & 0xFFu), 1u);
            }
            unsigned pa = wave_pick2<1>(myT, lane, rA, rA).a;
            unsigned pb = wave_pick2<1>(myB, lane, rB, rB).a;
            prefA |= (pa >> 12) << shift;  rA = pa & 0xFFFu;
            prefB |= (pb >> 12) << shift;  rB = pb & 0xFFFu;
        }
        known |= 0xFFu << shift;
    }

    float xlow  = ord2f(prefA);
    float xhigh = ord2f(prefB);
    float thr = xlow + (xhigh - xlow) * pc;

    // Epilogue: relu(x - thr) from register keys; nontemporal streaming stores
    // (output is never re-read -> don't evict input rows from L2/L3).
    v4f* outr = (v4f*)(out + (size_t)row * NELEM);
    #pragma unroll
    for (int j = 0; j < EPL / 4; ++j) {
        v4f o;
        o.x = fmaxf(ord2f(k[4 * j + 0]) - thr, 0.0f);
        o.y = fmaxf(ord2f(k[4 * j + 1]) - thr, 0.0f);
        o.z = fmaxf(ord2f(k[4 * j + 2]) - thr, 0.0f);
        o.w = fmaxf(ord2f(k[4 * j + 3]) - thr, 0.0f);
        __builtin_nontemporal_store(o, outr + j * 64 + lane);
    }
}

extern "C" void kernel_launch(void* const* d_in, const int* in_sizes, int n_in,
                              void* d_out, int out_size, void* d_ws, size_t ws_size,
                              hipStream_t stream) {
    const float* x      = (const float*)d_in[0];
    const float* plogit = (const float*)d_in[1];
    float* out          = (float*)d_out;
    int C    = in_sizes[1];              // 256
    int rows = in_sizes[0] / NELEM;      // 8192
    int grid = (rows + WPB - 1) / WPB;   // 2048 blocks of 4 independent row-waves
    xsrelu_kernel<<<grid, NTHREADS, 0, stream>>>(x, plogit, out, C, rows);
}